// Round 1
// baseline (15.374 us; speedup 1.0000x reference)
//
#include <hip/hip_runtime.h>
#include <math.h>

#define NQ 4
#define NP 196
#define IMG 784   // 28*28

// One block per image. Threads 0..195 each simulate one 2x2 patch's 4-qubit
// circuit fully in registers; partial logits reduced across the block.
__global__ __launch_bounds__(256) void quanv_fused_kernel(
    const float* __restrict__ x,       // [B, 784] (channel dim squeezed)
    const float* __restrict__ params,  // [2, 4]
    const float* __restrict__ W,       // [10, 784]
    const float* __restrict__ bias,    // [10]
    float* __restrict__ out)           // [B, 10]
{
    __shared__ float img[IMG];
    __shared__ float red[4][10];
    __shared__ float logit_s[10];

    const int b   = blockIdx.x;
    const int tid = threadIdx.x;

    // Stage image into LDS (coalesced: 256-thread stride)
    const float* xb = x + (size_t)b * IMG;
    for (int i = tid; i < IMG; i += 256) img[i] = xb[i];

    // Per-layer param half-angle cos/sin (8 sincos per thread; trivial,
    // broadcast loads hit constant path / L1)
    float pc[2][4], ps[2][4];
    #pragma unroll
    for (int l = 0; l < 2; ++l) {
        #pragma unroll
        for (int i = 0; i < 4; ++i) {
            __sincosf(0.5f * params[l * 4 + i], &ps[l][i], &pc[l][i]);
        }
    }

    __syncthreads();

    float pl[10];
    #pragma unroll
    for (int j = 0; j < 10; ++j) pl[j] = 0.0f;

    if (tid < NP) {
        const int pr = tid / 14;      // patch row
        const int pq = tid % 14;      // patch col
        // patch angles: [img[2pr,2pq], img[2pr,2pq+1], img[2pr+1,2pq], img[2pr+1,2pq+1]]
        const float a0 = img[(2 * pr) * 28 + 2 * pq];
        const float a1 = img[(2 * pr) * 28 + 2 * pq + 1];
        const float a2 = img[(2 * pr + 1) * 28 + 2 * pq];
        const float a3 = img[(2 * pr + 1) * 28 + 2 * pq + 1];

        float ci[4], si[4];
        __sincosf(0.5f * a0, &si[0], &ci[0]);
        __sincosf(0.5f * a1, &si[1], &ci[1]);
        __sincosf(0.5f * a2, &si[2], &ci[2]);
        __sincosf(0.5f * a3, &si[3], &ci[3]);

        // Product state after the 4 input RYs on |0000>.
        // Index k = q0*8 + q1*4 + q2*2 + q3 (wire i -> bit (3-i)).
        float st[16];
        #pragma unroll
        for (int k = 0; k < 16; ++k) {
            st[k] = (((k >> 3) & 1) ? si[0] : ci[0]) *
                    (((k >> 2) & 1) ? si[1] : ci[1]) *
                    (((k >> 1) & 1) ? si[2] : ci[2]) *
                    (((k >> 0) & 1) ? si[3] : ci[3]);
        }

        // 2 layers: RY(params[l][i]) on each wire, then CNOT (0,1),(1,2),(2,3),(3,0)
        #pragma unroll
        for (int l = 0; l < 2; ++l) {
            #pragma unroll
            for (int i = 0; i < 4; ++i) {
                const int m = 1 << (3 - i);
                const float c = pc[l][i], s = ps[l][i];
                #pragma unroll
                for (int k = 0; k < 16; ++k) {
                    if ((k & m) == 0) {
                        const float v0 = st[k], v1 = st[k | m];
                        st[k]     = c * v0 - s * v1;
                        st[k | m] = s * v0 + c * v1;
                    }
                }
            }
            #pragma unroll
            for (int e = 0; e < 4; ++e) {
                const int cw = e, tw = (e + 1) & 3;
                const int mc = 1 << (3 - cw), mt = 1 << (3 - tw);
                #pragma unroll
                for (int k = 0; k < 16; ++k) {
                    if ((k & mc) != 0 && (k & mt) == 0) {
                        const float tmp = st[k];
                        st[k]      = st[k | mt];
                        st[k | mt] = tmp;
                    }
                }
            }
        }

        // <Z_i> = sum_k st[k]^2 * (bit(3-i,k) ? -1 : +1)
        float z[4];
        #pragma unroll
        for (int i = 0; i < 4; ++i) {
            float acc = 0.0f;
            #pragma unroll
            for (int k = 0; k < 16; ++k) {
                const float p = st[k] * st[k];
                acc += (((k >> (3 - i)) & 1) ? -p : p);
            }
            z[i] = acc;
        }

        // Fold into partial logits. feats[b, tid*4 + i]; W row-major [10,784].
        // W + j*784 + tid*4 is 16B aligned -> float4 load, coalesced over tid.
        #pragma unroll
        for (int j = 0; j < 10; ++j) {
            const float4 w4 = *reinterpret_cast<const float4*>(W + j * IMG + tid * 4);
            pl[j] = z[0] * w4.x + z[1] * w4.y + z[2] * w4.z + z[3] * w4.w;
        }
    }

    // Wave (64-lane) shuffle reduction, then cross-wave via LDS
    #pragma unroll
    for (int j = 0; j < 10; ++j) {
        float v = pl[j];
        #pragma unroll
        for (int off = 32; off >= 1; off >>= 1) v += __shfl_down(v, off);
        pl[j] = v;
    }
    const int wave = tid >> 6;
    const int lane = tid & 63;
    if (lane == 0) {
        #pragma unroll
        for (int j = 0; j < 10; ++j) red[wave][j] = pl[j];
    }
    __syncthreads();

    if (tid < 10) {
        logit_s[tid] = red[0][tid] + red[1][tid] + red[2][tid] + red[3][tid] + bias[tid];
    }
    __syncthreads();

    if (tid < 10) {
        float m = -INFINITY;
        #pragma unroll
        for (int j = 0; j < 10; ++j) m = fmaxf(m, logit_s[j]);
        float sum = 0.0f;
        #pragma unroll
        for (int j = 0; j < 10; ++j) sum += __expf(logit_s[j] - m);
        out[b * 10 + tid] = logit_s[tid] - m - __logf(sum);
    }
}

extern "C" void kernel_launch(void* const* d_in, const int* in_sizes, int n_in,
                              void* d_out, int out_size, void* d_ws, size_t ws_size,
                              hipStream_t stream) {
    const float* x      = (const float*)d_in[0];  // [2048,1,28,28]
    const float* params = (const float*)d_in[1];  // [2,4]
    const float* W      = (const float*)d_in[2];  // [10,784]
    const float* bias   = (const float*)d_in[3];  // [10]
    float* out          = (float*)d_out;          // [2048,10]

    const int B = in_sizes[0] / IMG;              // 2048
    quanv_fused_kernel<<<B, 256, 0, stream>>>(x, params, W, bias, out);
}

// Round 2
// 14.829 us; speedup vs baseline: 1.0368x; 1.0368x over previous
//
#include <hip/hip_runtime.h>
#include <math.h>

#define NQ  4
#define NP  196
#define IMG 784   // 28*28
#define IPB 4     // images per block = one image per 64-lane wave

// Block = 256 threads = 4 waves; wave w owns image blockIdx.x*4 + w.
// Each lane simulates ~3 patches fully in registers, folds features into
// 10 partial-logit registers, wave shuffle-reduces, epilogue is wave-uniform.
__global__ __launch_bounds__(256) void quanv_fused_kernel(
    const float* __restrict__ x,       // [B, 784]
    const float* __restrict__ params,  // [2, 4]
    const float* __restrict__ W,       // [10, 784]
    const float* __restrict__ bias,    // [10]
    float* __restrict__ out,           // [B, 10]
    int B)
{
    __shared__ float img[IPB * IMG];

    const int tid  = threadIdx.x;
    const int wave = tid >> 6;
    const int lane = tid & 63;
    const int b    = blockIdx.x * IPB + wave;

    // Stage 4 consecutive images (contiguous 3136 floats) via float4, coalesced.
    {
        const int total4 = IPB * IMG / 4;            // 784 float4
        const size_t base4 = (size_t)blockIdx.x * total4;
        const float4* src = reinterpret_cast<const float4*>(x) + base4;
        float4* dst = reinterpret_cast<float4*>(img);
        #pragma unroll
        for (int i = 0; i < 4; ++i) {
            const int idx = tid + i * 256;
            if (idx < total4 && base4 + idx < (size_t)B * (IMG / 4)) dst[idx] = src[idx];
        }
    }

    // Param half-angle cos/sin (uniform; scalar-path loads)
    float pc[2][4], ps[2][4];
    #pragma unroll
    for (int l = 0; l < 2; ++l)
        #pragma unroll
        for (int i = 0; i < 4; ++i)
            __sincosf(0.5f * params[l * 4 + i], &ps[l][i], &pc[l][i]);

    __syncthreads();

    const float* my = img + wave * IMG;

    float pl[10];
    #pragma unroll
    for (int j = 0; j < 10; ++j) pl[j] = 0.0f;

    if (b < B) {
        #pragma unroll
        for (int it = 0; it < 4; ++it) {
            const int p = lane + it * 64;
            if (p < NP) {
                const int pr = p / 14;
                const int pq = p % 14;
                const float a0 = my[(2 * pr) * 28 + 2 * pq];
                const float a1 = my[(2 * pr) * 28 + 2 * pq + 1];
                const float a2 = my[(2 * pr + 1) * 28 + 2 * pq];
                const float a3 = my[(2 * pr + 1) * 28 + 2 * pq + 1];

                float ci[4], si[4];
                __sincosf(0.5f * a0, &si[0], &ci[0]);
                __sincosf(0.5f * a1, &si[1], &ci[1]);
                __sincosf(0.5f * a2, &si[2], &ci[2]);
                __sincosf(0.5f * a3, &si[3], &ci[3]);

                // Product state after input RYs. k = q0*8+q1*4+q2*2+q3.
                float st[16];
                #pragma unroll
                for (int k = 0; k < 16; ++k) {
                    st[k] = (((k >> 3) & 1) ? si[0] : ci[0]) *
                            (((k >> 2) & 1) ? si[1] : ci[1]) *
                            (((k >> 1) & 1) ? si[2] : ci[2]) *
                            (((k >> 0) & 1) ? si[3] : ci[3]);
                }

                // 2 layers: param RYs then ring CNOTs (0,1)(1,2)(2,3)(3,0)
                #pragma unroll
                for (int l = 0; l < 2; ++l) {
                    #pragma unroll
                    for (int i = 0; i < 4; ++i) {
                        const int m = 1 << (3 - i);
                        const float c = pc[l][i], s = ps[l][i];
                        #pragma unroll
                        for (int k = 0; k < 16; ++k) {
                            if ((k & m) == 0) {
                                const float v0 = st[k], v1 = st[k | m];
                                st[k]     = c * v0 - s * v1;
                                st[k | m] = s * v0 + c * v1;
                            }
                        }
                    }
                    #pragma unroll
                    for (int e = 0; e < 4; ++e) {
                        const int cw = e, tw = (e + 1) & 3;
                        const int mc = 1 << (3 - cw), mt = 1 << (3 - tw);
                        #pragma unroll
                        for (int k = 0; k < 16; ++k) {
                            if ((k & mc) != 0 && (k & mt) == 0) {
                                const float tmp = st[k];
                                st[k]      = st[k | mt];
                                st[k | mt] = tmp;
                            }
                        }
                    }
                }

                // <Z_i>
                float z[4];
                #pragma unroll
                for (int i = 0; i < 4; ++i) {
                    float acc = 0.0f;
                    #pragma unroll
                    for (int k = 0; k < 16; ++k) {
                        const float pk = st[k] * st[k];
                        acc += (((k >> (3 - i)) & 1) ? -pk : pk);
                    }
                    z[i] = acc;
                }

                // Fold into partial logits; W chunk 16B-aligned, coalesced over lanes.
                #pragma unroll
                for (int j = 0; j < 10; ++j) {
                    const float4 w4 = *reinterpret_cast<const float4*>(W + j * IMG + p * 4);
                    pl[j] += z[0] * w4.x + z[1] * w4.y + z[2] * w4.z + z[3] * w4.w;
                }
            }
        }
    }

    // Wave-internal butterfly reduce: every lane ends with the full sums.
    #pragma unroll
    for (int j = 0; j < 10; ++j) {
        float v = pl[j];
        #pragma unroll
        for (int off = 1; off < 64; off <<= 1) v += __shfl_xor(v, off);
        pl[j] = v;
    }

    if (b < B) {
        // Wave-uniform epilogue: bias + log_softmax, predicated stores.
        float lg[10];
        #pragma unroll
        for (int j = 0; j < 10; ++j) lg[j] = pl[j] + bias[j];
        float m = lg[0];
        #pragma unroll
        for (int j = 1; j < 10; ++j) m = fmaxf(m, lg[j]);
        float sum = 0.0f;
        #pragma unroll
        for (int j = 0; j < 10; ++j) sum += __expf(lg[j] - m);
        const float ls = __logf(sum);
        #pragma unroll
        for (int j = 0; j < 10; ++j) {
            if (lane == j) out[(size_t)b * 10 + j] = lg[j] - m - ls;
        }
    }
}

extern "C" void kernel_launch(void* const* d_in, const int* in_sizes, int n_in,
                              void* d_out, int out_size, void* d_ws, size_t ws_size,
                              hipStream_t stream) {
    const float* x      = (const float*)d_in[0];  // [2048,1,28,28]
    const float* params = (const float*)d_in[1];  // [2,4]
    const float* W      = (const float*)d_in[2];  // [10,784]
    const float* bias   = (const float*)d_in[3];  // [10]
    float* out          = (float*)d_out;          // [2048,10]

    const int B = in_sizes[0] / IMG;              // 2048
    const int grid = (B + IPB - 1) / IPB;         // 512
    quanv_fused_kernel<<<grid, 256, 0, stream>>>(x, params, W, bias, out, B);
}

// Round 3
// 13.315 us; speedup vs baseline: 1.1546x; 1.1136x over previous
//
#include <hip/hip_runtime.h>
#include <math.h>

#define NQ  4
#define NP  196
#define IMG 784   // 28*28

// One block (4 waves) per image. Wave w owns patches [w*49, w*49+49); each
// lane simulates exactly one patch (lane<49). Layer-0 param RYs are merged
// into the input RYs (same-axis rotations compose), halving RY sweeps.
__global__ __launch_bounds__(256) void quanv_fused_kernel(
    const float* __restrict__ x,       // [B, 784]
    const float* __restrict__ params,  // [2, 4]
    const float* __restrict__ W,       // [10, 784]
    const float* __restrict__ bias,    // [10]
    float* __restrict__ out)           // [B, 10]
{
    __shared__ float img[IMG];
    __shared__ float red[4][10];
    __shared__ float logit_s[10];

    const int b    = blockIdx.x;
    const int tid  = threadIdx.x;
    const int wave = tid >> 6;
    const int lane = tid & 63;

    // Stage image (784 floats = 196 float4), coalesced.
    if (tid < IMG / 4) {
        reinterpret_cast<float4*>(img)[tid] =
            reinterpret_cast<const float4*>(x + (size_t)b * IMG)[tid];
    }

    // Uniform params: layer-0 angles kept raw (merged with data angles),
    // layer-1 half-angle cos/sin.
    float p0[4], pc1[4], ps1[4];
    #pragma unroll
    for (int i = 0; i < 4; ++i) {
        p0[i] = params[i];
        __sincosf(0.5f * params[4 + i], &ps1[i], &pc1[i]);
    }

    __syncthreads();

    float pl[10];
    #pragma unroll
    for (int j = 0; j < 10; ++j) pl[j] = 0.0f;

    const int p = wave * 49 + lane;          // patch id, 0..195
    if (lane < 49) {
        const int pr = p / 14;
        const int pq = p % 14;
        const float a0 = img[(2 * pr) * 28 + 2 * pq];
        const float a1 = img[(2 * pr) * 28 + 2 * pq + 1];
        const float a2 = img[(2 * pr + 1) * 28 + 2 * pq];
        const float a3 = img[(2 * pr + 1) * 28 + 2 * pq + 1];

        // Merged input+layer0 RYs: product state with angles a_i + p0_i.
        float ci[4], si[4];
        __sincosf(0.5f * (a0 + p0[0]), &si[0], &ci[0]);
        __sincosf(0.5f * (a1 + p0[1]), &si[1], &ci[1]);
        __sincosf(0.5f * (a2 + p0[2]), &si[2], &ci[2]);
        __sincosf(0.5f * (a3 + p0[3]), &si[3], &ci[3]);

        // st[k], k = q0*8 + q1*4 + q2*2 + q3
        float A[4]  = { ci[0]*ci[1], ci[0]*si[1], si[0]*ci[1], si[0]*si[1] };
        float Bp[4] = { ci[2]*ci[3], ci[2]*si[3], si[2]*ci[3], si[2]*si[3] };
        float st[16];
        #pragma unroll
        for (int u = 0; u < 4; ++u)
            #pragma unroll
            for (int v = 0; v < 4; ++v)
                st[u * 4 + v] = A[u] * Bp[v];

        // CNOT ring #1 (0,1)(1,2)(2,3)(3,0): compile-time register swaps.
        #pragma unroll
        for (int e = 0; e < 4; ++e) {
            const int mc = 1 << (3 - e), mt = 1 << (3 - ((e + 1) & 3));
            #pragma unroll
            for (int k = 0; k < 16; ++k) {
                if ((k & mc) != 0 && (k & mt) == 0) {
                    const float tmp = st[k];
                    st[k]      = st[k | mt];
                    st[k | mt] = tmp;
                }
            }
        }

        // Layer-1 RYs (the only remaining rotation sweeps).
        #pragma unroll
        for (int i = 0; i < 4; ++i) {
            const int m = 1 << (3 - i);
            const float c = pc1[i], s = ps1[i];
            #pragma unroll
            for (int k = 0; k < 16; ++k) {
                if ((k & m) == 0) {
                    const float v0 = st[k], v1 = st[k | m];
                    st[k]     = c * v0 - s * v1;
                    st[k | m] = s * v0 + c * v1;
                }
            }
        }

        // CNOT ring #2.
        #pragma unroll
        for (int e = 0; e < 4; ++e) {
            const int mc = 1 << (3 - e), mt = 1 << (3 - ((e + 1) & 3));
            #pragma unroll
            for (int k = 0; k < 16; ++k) {
                if ((k & mc) != 0 && (k & mt) == 0) {
                    const float tmp = st[k];
                    st[k]      = st[k | mt];
                    st[k | mt] = tmp;
                }
            }
        }

        // Squares + shared Walsh tree for the four <Z_i>.
        float pk[16];
        #pragma unroll
        for (int k = 0; k < 16; ++k) pk[k] = st[k] * st[k];

        float s1[8], d1[8];
        #pragma unroll
        for (int k = 0; k < 8; ++k) { s1[k] = pk[2*k] + pk[2*k+1]; d1[k] = pk[2*k] - pk[2*k+1]; }
        const float z3 = ((d1[0]+d1[1]) + (d1[2]+d1[3])) + ((d1[4]+d1[5]) + (d1[6]+d1[7]));

        float s2[4], d2[4];
        #pragma unroll
        for (int k = 0; k < 4; ++k) { s2[k] = s1[2*k] + s1[2*k+1]; d2[k] = s1[2*k] - s1[2*k+1]; }
        const float z2 = (d2[0] + d2[1]) + (d2[2] + d2[3]);

        const float s3a = s2[0] + s2[1], s3b = s2[2] + s2[3];
        const float z1  = (s2[0] - s2[1]) + (s2[2] - s2[3]);
        const float z0  = s3a - s3b;

        // Fold into partial logits; 16B-aligned coalesced W reads.
        #pragma unroll
        for (int j = 0; j < 10; ++j) {
            const float4 w4 = *reinterpret_cast<const float4*>(W + j * IMG + p * 4);
            pl[j] = z0 * w4.x + z1 * w4.y + z2 * w4.z + z3 * w4.w;
        }
    }

    // Wave shuffle-reduce, then cross-wave via LDS.
    #pragma unroll
    for (int j = 0; j < 10; ++j) {
        float v = pl[j];
        #pragma unroll
        for (int off = 32; off >= 1; off >>= 1) v += __shfl_down(v, off);
        pl[j] = v;
    }
    if (lane == 0) {
        #pragma unroll
        for (int j = 0; j < 10; ++j) red[wave][j] = pl[j];
    }
    __syncthreads();

    if (tid < 10) {
        logit_s[tid] = red[0][tid] + red[1][tid] + red[2][tid] + red[3][tid] + bias[tid];
    }
    __syncthreads();

    if (tid < 10) {
        float m = -INFINITY;
        #pragma unroll
        for (int j = 0; j < 10; ++j) m = fmaxf(m, logit_s[j]);
        float sum = 0.0f;
        #pragma unroll
        for (int j = 0; j < 10; ++j) sum += __expf(logit_s[j] - m);
        out[(size_t)b * 10 + tid] = logit_s[tid] - m - __logf(sum);
    }
}

extern "C" void kernel_launch(void* const* d_in, const int* in_sizes, int n_in,
                              void* d_out, int out_size, void* d_ws, size_t ws_size,
                              hipStream_t stream) {
    const float* x      = (const float*)d_in[0];  // [2048,1,28,28]
    const float* params = (const float*)d_in[1];  // [2,4]
    const float* W      = (const float*)d_in[2];  // [10,784]
    const float* bias   = (const float*)d_in[3];  // [10]
    float* out          = (float*)d_out;          // [2048,10]

    const int B = in_sizes[0] / IMG;              // 2048
    quanv_fused_kernel<<<B, 256, 0, stream>>>(x, params, W, bias, out);
}

// Round 5
// 10.579 us; speedup vs baseline: 1.4532x; 1.2587x over previous
//
#include <hip/hip_runtime.h>
#include <math.h>

#define IMG 784   // 28*28
#define NP  196

// Wave-per-image, FULLY CONVERGENT body: no lane-divergent branches anywhere
// before the final store predicate. Each lane handles patches {lane, lane+64,
// lane+128, lane+192}; p>=196 lanes clamp to patch 195 (in-bounds loads) and
// zero their z contributions. Closed-form Pauli propagation (verified exact):
//   C_q=cos(a_q+p0_q), S_q=sin(a_q+p0_q), k_q=cos(p1_q), s_q=sin(p1_q).
__global__ __launch_bounds__(256) void quanv_fused_kernel(
    const float* __restrict__ x,       // [B, 784]
    const float* __restrict__ params,  // [2, 4]
    const float* __restrict__ W,       // [10, 784]
    const float* __restrict__ bias,    // [10]
    float* __restrict__ out,           // [B, 10]
    int B)
{
    const int tid  = threadIdx.x;
    const int wave = tid >> 6;
    const int lane = tid & 63;
    const int b    = blockIdx.x * 4 + wave;
    const int bb   = (b < B) ? b : 0;          // wave-uniform clamp
    const float* xb = x + (size_t)bb * IMG;

    // Wave-uniform circuit coefficients.
    const float p00 = params[0], p01 = params[1], p02 = params[2], p03 = params[3];
    float k0, k1, k2, k3, s0, s1, s2, s3;
    __sincosf(params[4], &s0, &k0);
    __sincosf(params[5], &s1, &k1);
    __sincosf(params[6], &s2, &k2);
    __sincosf(params[7], &s3, &k3);

    const float A00 = k1*k2*k3,    A01 = -k1*k2*s3,    A02 = -s1*k2*k3,   A03 = -s1*s2*s3;
    const float A10 = k0*k1,       A11 = s0*s1;
    const float A20 = k0*k1*k2,    A21 = -k0*s1*k2,    A22 = -s0*k1*k2,   A23 = -s0*s1*s2;
    const float A30 = k0*k1*k2*k3, A31 = -k0*k1*s2*k3, A32 = k0*s1*s2*k3, A33 = -k0*s1*s2*s3;
    const float A34 = s0*k1*k2*s3, A35 = -s0*k1*s2*s3, A36 = s0*s1*k2*k3, A37 = s0*s1*s2*s3;

    float pl[10];
    #pragma unroll
    for (int j = 0; j < 10; ++j) pl[j] = 0.f;

    #pragma unroll
    for (int it = 0; it < 4; ++it) {
        const int   p   = lane + it * 64;           // 0..255
        const bool  ok  = (p < NP);
        const int   pc  = ok ? p : (NP - 1);        // clamped, loads in-bounds
        const float msk = ok ? 1.f : 0.f;

        const int pr = pc / 14;
        const int pq = pc % 14;
        const float2 r0 = *reinterpret_cast<const float2*>(xb + pr * 56 + pq * 2);
        const float2 r1 = *reinterpret_cast<const float2*>(xb + pr * 56 + 28 + pq * 2);

        float C0, C1, C2, C3, S0, S1, S2, S3;
        __sincosf(r0.x + p00, &S0, &C0);
        __sincosf(r0.y + p01, &S1, &C1);
        __sincosf(r1.x + p02, &S2, &C2);
        __sincosf(r1.y + p03, &S3, &C3);

        const float C0C1 = C0*C1, C2C3 = C2*C3, C0C2 = C0*C2;
        const float C1C3 = C1*C3, C0C3 = C0*C3, C2S3 = C2*S3;
        const float S0S1 = S0*S1, S2S3 = S2*S3, S0S2 = S0*S2;
        const float S1S2 = S1*S2, S0S3 = S0*S3, S1S3 = S1*S3;

        const float z0 = msk * (A00*(C0C1*C3) + A01*(S0S1*C2S3) + A02*(S1S2*C3) + A03*S0);
        const float z1 = msk * (A10*(C2C3*C0) + A11*S0S2);
        const float z2 = msk * (A20*C1C3 + A21*(S1S2*C0C3) + A22*(S0S1*C2) + A23*S0S3);
        const float z3 = msk * (A30*C0C2 + A31*(S2S3*C1) + A32*(S1S3*C0)
                              + A33*((C2C3*C1)*S0) + A34*C2S3 + A35*(C0C1*S2)
                              + A36*(S0S2*C3) + A37*S1);

        #pragma unroll
        for (int j = 0; j < 10; ++j) {
            const float4 w4 = *reinterpret_cast<const float4*>(W + j * IMG + pc * 4);
            pl[j] += z0 * w4.x + z1 * w4.y + z2 * w4.z + z3 * w4.w;
        }
    }

    // Full-exec butterfly reduction: every lane ends with all 10 logit sums.
    #pragma unroll
    for (int off = 1; off < 64; off <<= 1) {
        #pragma unroll
        for (int j = 0; j < 10; ++j) pl[j] += __shfl_xor(pl[j], off);
    }

    // Wave-uniform log-softmax epilogue.
    float lg[10];
    #pragma unroll
    for (int j = 0; j < 10; ++j) lg[j] = pl[j] + bias[j];
    float m = lg[0];
    #pragma unroll
    for (int j = 1; j < 10; ++j) m = fmaxf(m, lg[j]);
    float sum = 0.f;
    #pragma unroll
    for (int j = 0; j < 10; ++j) sum += __expf(lg[j] - m);
    const float ls = __logf(sum);

    float v = lg[0];
    #pragma unroll
    for (int j = 1; j < 10; ++j) v = (lane == j) ? lg[j] : v;
    if (lane < 10 && b < B) out[(size_t)b * 10 + lane] = v - m - ls;
}

extern "C" void kernel_launch(void* const* d_in, const int* in_sizes, int n_in,
                              void* d_out, int out_size, void* d_ws, size_t ws_size,
                              hipStream_t stream) {
    const float* x      = (const float*)d_in[0];  // [2048,1,28,28]
    const float* params = (const float*)d_in[1];  // [2,4]
    const float* W      = (const float*)d_in[2];  // [10,784]
    const float* bias   = (const float*)d_in[3];  // [10]
    float* out          = (float*)d_out;          // [2048,10]

    const int B = in_sizes[0] / IMG;              // 2048
    const int grid = (B + 3) / 4;                 // 512
    quanv_fused_kernel<<<grid, 256, 0, stream>>>(x, params, W, bias, out, B);
}